// Round 4
// baseline (166.593 us; speedup 1.0000x reference)
//
#include <hip/hip_runtime.h>
#include <math.h>

#define SEQ 2048
#define NH 8
#define HD 128
#define DIMF 1024
#define LOG2E 1.4426950408889634f
#define INVTAU 0.08838834764831845f

typedef __attribute__((ext_vector_type(8))) short bf16x8;
typedef __attribute__((ext_vector_type(8))) unsigned short us8;
typedef __attribute__((ext_vector_type(4))) float f32x4;

// persistent scratch (fully rewritten every launch; no stale-state dependence)
__device__ float g_itacc[NH*SEQ];
__device__ float g_ftacc[NH*SEQ];
__device__ float g_aL[NH*SEQ];     // (itilde - csum) * log2e
__device__ float g_cmL[NH*SEQ];    // cummax(a) * log2e
__device__ float g_en[NH*SEQ];     // exp(-(csum + cummax)) = exp(-max_d)
__device__ unsigned short g_Qb[NH*SEQ*HD];  // bf16, [h][s][d]
__device__ unsigned short g_Kb[NH*SEQ*HD];
__device__ unsigned short g_Vb[NH*SEQ*HD];
__device__ unsigned short g_Vt[NH*HD*SEQ];  // bf16, [h][d][s]  (V transposed)
__device__ unsigned short g_Wb[16*3072];    // bf16, rows 0..7 = Wi, 8..15 = Wf
// j-chunk partials: 640 slots (8 heads x 80 chunk-slots)
__device__ float g_Opart[640*64*128];       // fp32 partial O tiles
__device__ float g_Spart[640*64];           // fp32 partial rowsums

__device__ __forceinline__ unsigned short f2bf(float x) {
  unsigned u = __float_as_uint(x);
  u += 0x7fffu + ((u >> 16) & 1u);   // RNE
  return (unsigned short)(u >> 16);
}

// ------- kernel 1: q/k fp32 -> bf16 [h][s][d]  +  Wi/Wf -> bf16 -------
__global__ __launch_bounds__(256) void convert_kernel(const float* __restrict__ q,
                                                      const float* __restrict__ k,
                                                      const float* __restrict__ Wi,
                                                      const float* __restrict__ Wf) {
  const int bid = blockIdx.x;
  if (bid < 4096) {
    const int s = bid & 2047;
    const int t = bid >> 11;
    const float* src = (t == 0) ? q : k;
    unsigned short* dst = (t == 0) ? g_Qb : g_Kb;
    const int c = threadIdx.x * 4;
    const float4 f = *(const float4*)(src + s*DIMF + c);
    const int h = c >> 7, d = c & 127;
    ushort4 u;
    u.x = f2bf(f.x); u.y = f2bf(f.y); u.z = f2bf(f.z); u.w = f2bf(f.w);
    *(ushort4*)(dst + (h*SEQ + s)*HD + d) = u;
  } else {
    const int gid = (bid - 4096) * 256 + threadIdx.x;
    const int e4 = gid * 4;           // 48 blocks * 1024 = 49152 = 16*3072 exactly
    const int p = e4 / 3072;
    const int c = e4 % 3072;
    const float* src = (p < 8) ? (Wi + p*3072 + c) : (Wf + (p-8)*3072 + c);
    const float4 f = *(const float4*)src;
    ushort4 u;
    u.x = f2bf(f.x); u.y = f2bf(f.y); u.z = f2bf(f.z); u.w = f2bf(f.w);
    *(ushort4*)(g_Wb + p*3072 + c) = u;
  }
}

// ------- kernel 2: V fp32 -> bf16, writes BOTH g_Vb[h][s][d] and g_Vt[h][d][s] -------
__global__ __launch_bounds__(256) void vtrans_kernel(const float* __restrict__ v) {
  __shared__ __align__(16) unsigned short Ts[64*72];
  const int h  = blockIdx.x;
  const int s0 = blockIdx.y * 64;
  const int d0 = blockIdx.z * 64;
  const int t = threadIdx.x;
  { // load 64 s-rows x 64 d-cols fp32, convert, stash to LDS + g_Vb
    const int sr = t >> 2;
    const int c  = (t & 3) * 16;
    const float* src = v + (s0 + sr)*DIMF + h*HD + d0 + c;
    unsigned short tmp[16];
    #pragma unroll
    for (int i = 0; i < 4; ++i) {
      const float4 f = *(const float4*)&src[i*4];
      tmp[i*4+0] = f2bf(f.x); tmp[i*4+1] = f2bf(f.y);
      tmp[i*4+2] = f2bf(f.z); tmp[i*4+3] = f2bf(f.w);
    }
    *(us8*)&Ts[sr*72 + c]     = *(us8*)&tmp[0];
    *(us8*)&Ts[sr*72 + c + 8] = *(us8*)&tmp[8];
    unsigned short* vb = g_Vb + (h*SEQ + s0 + sr)*HD + d0 + c;
    *(us8*)&vb[0] = *(us8*)&tmp[0];
    *(us8*)&vb[8] = *(us8*)&tmp[8];
  }
  __syncthreads();
  { // transposed store: wave w covers s-cols [w*16,w*16+16), lane l = d-row
    const int w = t >> 6, l = t & 63;
    unsigned short outv[16];
    #pragma unroll
    for (int j = 0; j < 16; ++j) outv[j] = Ts[(w*16 + j)*72 + l];
    unsigned short* dst = g_Vt + (h*HD + d0 + l)*SEQ + s0 + w*16;
    *(us8*)&dst[0] = *(us8*)&outv[0];
    *(us8*)&dst[8] = *(us8*)&outv[8];
  }
}

// ------- kernel 3: gate projections via MFMA (M=2048, N=16, K=3072) -------
__global__ __launch_bounds__(256) void gates_kernel() {
  __shared__ f32x4 red[4][64];
  const int tid = threadIdx.x;
  const int wave = tid >> 6, lane = tid & 63;
  const int q4 = lane >> 4, l16 = lane & 15;
  const int s0 = blockIdx.x * 16;
  f32x4 acc = {0.f, 0.f, 0.f, 0.f};
  #pragma unroll 8
  for (int ks = wave*24; ks < wave*24 + 24; ++ks) {
    const int k0 = ks*32 + q4*8;          // global k of this lane's 8 elems
    const int tsel = k0 >> 10;
    const int rem = k0 & 1023;
    const int hh = rem >> 7, dd = rem & 127;
    const unsigned short* base = (tsel == 0) ? g_Qb : (tsel == 1) ? g_Kb : g_Vb;
    const bf16x8 a = *(const bf16x8*)&base[(hh*SEQ + s0 + l16)*HD + dd];
    const bf16x8 b = *(const bf16x8*)&g_Wb[l16*3072 + k0];
    acc = __builtin_amdgcn_mfma_f32_16x16x32_bf16(a, b, acc, 0, 0, 0);
  }
  red[wave][lane] = acc;
  __syncthreads();
  if (wave == 0) {
    f32x4 s = red[0][lane];
    #pragma unroll
    for (int w = 1; w < 4; ++w) s += red[w][lane];
    #pragma unroll
    for (int r = 0; r < 4; ++r) {
      const int sg = s0 + 4*q4 + r;       // C/D: row = quad*4+reg, col = l16
      if (l16 < 8) g_itacc[l16*SEQ + sg] = s[r];
      else         g_ftacc[(l16-8)*SEQ + sg] = s[r];
    }
  }
}

// ------- kernel 4: per-head scans (block scan, 256 threads, 8 elems/thread) -------
__global__ __launch_bounds__(256) void scan_kernel(const float* __restrict__ Wi_b,
                                                   const float* __restrict__ Wf_b) {
  __shared__ float Wsum[4];
  __shared__ float Wmax[4];
  const int h = blockIdx.x;
  const int t = threadIdx.x;
  const int wave = t >> 6, lane = t & 63;
  const float ib = Wi_b[h];
  const float fb = Wf_b[h];
  const int base = h*SEQ + t*8;

  float it[8], ft[8];
  *(float4*)&it[0] = *(const float4*)&g_itacc[base];
  *(float4*)&it[4] = *(const float4*)&g_itacc[base+4];
  *(float4*)&ft[0] = *(const float4*)&g_ftacc[base];
  *(float4*)&ft[4] = *(const float4*)&g_ftacc[base+4];

  float cs[8];
  float run = 0.f;
  #pragma unroll
  for (int j = 0; j < 8; ++j) {
    const float f = ft[j] + fb;
    const float ls = fminf(f, 0.f) - log1pf(expf(-fabsf(f)));  // logsigmoid
    run += ls;
    cs[j] = run;
  }
  float x = run;
  #pragma unroll
  for (int off = 1; off < 64; off <<= 1) {
    const float tv = __shfl_up(x, off, 64);
    if (lane >= off) x += tv;
  }
  const float wexcl = x - run;
  if (lane == 63) Wsum[wave] = x;
  __syncthreads();
  float boff = 0.f;
  #pragma unroll
  for (int w = 0; w < 4; ++w) if (w < wave) boff += Wsum[w];
  const float cbase = boff + wexcl;

  float a[8], am[8], csum[8];
  float m = -__builtin_inff();
  #pragma unroll
  for (int j = 0; j < 8; ++j) {
    csum[j] = cbase + cs[j];
    a[j] = (it[j] + ib) - csum[j];
    m = fmaxf(m, a[j]);
    am[j] = m;
  }
  float y = m;
  #pragma unroll
  for (int off = 1; off < 64; off <<= 1) {
    const float tv = __shfl_up(y, off, 64);
    if (lane >= off) y = fmaxf(y, tv);
  }
  float e = __shfl_up(y, 1, 64);
  if (lane == 0) e = -__builtin_inff();
  if (lane == 63) Wmax[wave] = y;
  __syncthreads();
  float bmax = -__builtin_inff();
  #pragma unroll
  for (int w = 0; w < 4; ++w) if (w < wave) bmax = fmaxf(bmax, Wmax[w]);
  const float pre = fmaxf(bmax, e);

  float oa[8], ocm[8], oen[8];
  #pragma unroll
  for (int j = 0; j < 8; ++j) {
    const float cm = fmaxf(pre, am[j]);
    oa[j]  = a[j] * LOG2E;
    ocm[j] = cm * LOG2E;
    oen[j] = expf(-(csum[j] + cm));
  }
  *(float4*)&g_aL[base]    = *(float4*)&oa[0];
  *(float4*)&g_aL[base+4]  = *(float4*)&oa[4];
  *(float4*)&g_cmL[base]   = *(float4*)&ocm[0];
  *(float4*)&g_cmL[base+4] = *(float4*)&ocm[4];
  *(float4*)&g_en[base]    = *(float4*)&oen[0];
  *(float4*)&g_en[base+4]  = *(float4*)&oen[4];
}

// ------- kernel 5: j-chunked decay attention, 1 barrier/iter, no K/V LDS -------
// grid = (8 heads, 80 chunk-slots); linear%8 pins head->XCD (K/V L2-resident).
// K and V^T B-fragments load straight global->VGPR (B-frag = row slice of
// row-major K / V^T). Only P round-trips LDS (C-layout -> A-layout), double-
// buffered so each j-iteration has exactly ONE __syncthreads.
__global__ __launch_bounds__(256, 3) void attn1_kernel() {
  __shared__ __align__(16) unsigned short Ps[2][64*72];
  __shared__ float Sred[64][2];

  const int h = blockIdx.x;
  const int y = blockIdx.y;
  int g, s0g;
  if      (y < 8)  { g = 0; s0g = 0;  }
  else if (y < 24) { g = 1; s0g = 8;  }
  else if (y < 48) { g = 2; s0g = 24; }
  else             { g = 3; s0g = 48; }
  const int rel = y - s0g;
  const int iT  = 8*g + rel/(g+1);
  const int ch  = rel - (rel/(g+1))*(g+1);
  const int slot = h*80 + y;
  const int i0 = iT*64;
  const int jt0 = ch*8;
  const int jt1 = (jt0 + 8 < iT + 1) ? (jt0 + 8) : (iT + 1);

  const int tid = threadIdx.x;
  const int wave = tid >> 6;
  const int lane = tid & 63;
  const int q4 = lane >> 4;
  const int l16 = lane & 15;
  const int wr = wave >> 1;
  const int wc = wave & 1;

  // Q A-fragments in registers for the whole block
  bf16x8 qa[2][4];
  {
    const unsigned short* Qg = g_Qb + (h*SEQ + i0 + 32*wr + l16)*HD;
    #pragma unroll
    for (int tr = 0; tr < 2; ++tr)
      #pragma unroll
      for (int ks = 0; ks < 4; ++ks)
        qa[tr][ks] = *(const bf16x8*)&Qg[tr*16*HD + ks*32 + q4*8];
  }

  float cmv[2][4];
  #pragma unroll
  for (int tr = 0; tr < 2; ++tr)
    #pragma unroll
    for (int r = 0; r < 4; ++r)
      cmv[tr][r] = g_cmL[h*SEQ + i0 + 32*wr + 16*tr + 4*q4 + r];

  f32x4 accH[2][4];
  float rs[2][4];
  const f32x4 fzero = {0.f, 0.f, 0.f, 0.f};
  #pragma unroll
  for (int tr = 0; tr < 2; ++tr) {
    #pragma unroll
    for (int tc = 0; tc < 4; ++tc) accH[tr][tc] = fzero;
    #pragma unroll
    for (int r = 0; r < 4; ++r) rs[tr][r] = 0.f;
  }

  const unsigned short* Kgh = g_Kb + (h*SEQ)*HD;
  const unsigned short* Vgh = g_Vt + (h*HD)*SEQ;

  for (int jt = jt0; jt < jt1; ++jt) {
    const int j0 = jt*64;
    const int b = (jt - jt0) & 1;
    unsigned short* Pb = &Ps[b][0];

    // gate factors for this wave's j-columns
    float aLv[2];
    aLv[0] = g_aL[h*SEQ + j0 + 32*wc + l16];
    aLv[1] = g_aL[h*SEQ + j0 + 32*wc + 16 + l16];

    // QK^T: A = Q regs, B = K rows direct from global (L2-resident)
    f32x4 c00 = fzero, c01 = fzero, c10 = fzero, c11 = fzero;
    #pragma unroll
    for (int ks = 0; ks < 4; ++ks) {
      const int ko = ks*32 + q4*8;
      const bf16x8 b0 = *(const bf16x8*)&Kgh[(j0 + 32*wc      + l16)*HD + ko];
      const bf16x8 b1 = *(const bf16x8*)&Kgh[(j0 + 32*wc + 16 + l16)*HD + ko];
      c00 = __builtin_amdgcn_mfma_f32_16x16x32_bf16(qa[0][ks], b0, c00, 0, 0, 0);
      c01 = __builtin_amdgcn_mfma_f32_16x16x32_bf16(qa[0][ks], b1, c01, 0, 0, 0);
      c10 = __builtin_amdgcn_mfma_f32_16x16x32_bf16(qa[1][ks], b0, c10, 0, 0, 0);
      c11 = __builtin_amdgcn_mfma_f32_16x16x32_bf16(qa[1][ks], b1, c11, 0, 0, 0);
    }

    // P = (dot/TAU) * exp2(aL_j - cmL_i), causal mask on diagonal tile
    const bool diag = (jt == iT);
    #pragma unroll
    for (int tr = 0; tr < 2; ++tr) {
      #pragma unroll
      for (int tc = 0; tc < 2; ++tc) {
        const f32x4 cc = tr ? (tc ? c11 : c10) : (tc ? c01 : c00);
        const int jg = j0 + 32*wc + 16*tc + l16;
        #pragma unroll
        for (int r = 0; r < 4; ++r) {
          const int rloc = 32*wr + 16*tr + 4*q4 + r;
          const int ig = i0 + rloc;
          const float w = exp2f(aLv[tc] - cmv[tr][r]) * INVTAU;
          float p = cc[r] * w;
          if (diag && (jg > ig)) p = 0.f;
          rs[tr][r] += p;
          Pb[rloc*72 + 32*wc + 16*tc + l16] = f2bf(p);
        }
      }
    }
    __syncthreads();   // the ONLY barrier: P_n visible; also fences buffer reuse

    // PV: A = P rows (LDS), B = V^T rows direct from global
    #pragma unroll
    for (int ks = 0; ks < 2; ++ks) {
      const int ko = ks*32 + q4*8;
      const bf16x8 p0 = *(const bf16x8*)&Pb[(32*wr      + l16)*72 + ko];
      const bf16x8 p1 = *(const bf16x8*)&Pb[(32*wr + 16 + l16)*72 + ko];
      #pragma unroll
      for (int tc = 0; tc < 4; ++tc) {
        const bf16x8 vb = *(const bf16x8*)&Vgh[(64*wc + 16*tc + l16)*SEQ + j0 + ko];
        accH[0][tc] = __builtin_amdgcn_mfma_f32_16x16x32_bf16(p0, vb, accH[0][tc], 0, 0, 0);
        accH[1][tc] = __builtin_amdgcn_mfma_f32_16x16x32_bf16(p1, vb, accH[1][tc], 0, 0, 0);
      }
    }
  }

  // rowsum reduce across 16 column-lanes; combine wc halves via LDS
  #pragma unroll
  for (int tr = 0; tr < 2; ++tr)
    #pragma unroll
    for (int r = 0; r < 4; ++r) {
      float t = rs[tr][r];
      t += __shfl_xor(t, 1, 16);
      t += __shfl_xor(t, 2, 16);
      t += __shfl_xor(t, 4, 16);
      t += __shfl_xor(t, 8, 16);
      rs[tr][r] = t;
    }
  if (l16 == 0) {
    #pragma unroll
    for (int tr = 0; tr < 2; ++tr)
      #pragma unroll
      for (int r = 0; r < 4; ++r)
        Sred[32*wr + 16*tr + 4*q4 + r][wc] = rs[tr][r];
  }
  __syncthreads();

  if (tid < 64) g_Spart[slot*64 + tid] = Sred[tid][0] + Sred[tid][1];

  float* Ob = g_Opart + slot*(64*128);
  #pragma unroll
  for (int tr = 0; tr < 2; ++tr)
    #pragma unroll
    for (int r = 0; r < 4; ++r) {
      const int rloc = 32*wr + 16*tr + 4*q4 + r;
      #pragma unroll
      for (int tc = 0; tc < 4; ++tc)
        Ob[rloc*128 + 64*wc + 16*tc + l16] = accH[tr][tc][r];
    }
}

// ------- kernel 6: reduce partials + maxit normalize + GroupNorm -------
__global__ __launch_bounds__(256) void reduce_kernel(const float* __restrict__ gnw,
                                                     const float* __restrict__ gnb,
                                                     float* __restrict__ out) {
  const int h  = blockIdx.x;
  const int iT = blockIdx.y;
  const int t  = threadIdx.x;
  const int r  = t >> 2;
  const int qd = t & 3;
  const int qq = iT >> 3;
  const int nch = qq + 1;
  const int slot0 = h*80 + iT + 4*qq*(qq-1) + qq*(iT & 7);

  float acc[32];
  #pragma unroll
  for (int e = 0; e < 32; ++e) acc[e] = 0.f;
  float S = 0.f;
  for (int c = 0; c < nch; ++c) {
    const float* Ob = g_Opart + (slot0 + c)*(64*128) + r*128 + qd*32;
    #pragma unroll
    for (int kk = 0; kk < 8; ++kk) {
      const float4 f = *(const float4*)&Ob[kk*4];
      acc[kk*4+0] += f.x; acc[kk*4+1] += f.y; acc[kk*4+2] += f.z; acc[kk*4+3] += f.w;
    }
    S += g_Spart[(slot0 + c)*64 + r];
  }

  const float en = g_en[h*SEQ + iT*64 + r];
  const float sc = 1.f / (fmaxf(fabsf(S), en) + 1e-6f);
  float s1 = 0.f, s2 = 0.f;
  #pragma unroll
  for (int e = 0; e < 32; ++e) {
    const float xv = acc[e] * sc;
    acc[e] = xv;
    s1 += xv;
    s2 += xv * xv;
  }
  s1 += __shfl_xor(s1, 1, 4); s2 += __shfl_xor(s2, 1, 4);
  s1 += __shfl_xor(s1, 2, 4); s2 += __shfl_xor(s2, 2, 4);
  const float mean = s1 * (1.f/128.f);
  const float var  = s2 * (1.f/128.f) - mean*mean;
  const float rstd = rsqrtf(var + 1e-5f);

  const float* gw = gnw + h*HD + qd*32;
  const float* gb = gnb + h*HD + qd*32;
  float* op = out + (iT*64 + r)*DIMF + h*HD + qd*32;
  #pragma unroll
  for (int kk = 0; kk < 8; ++kk) {
    const float4 w4 = *(const float4*)&gw[kk*4];
    const float4 b4 = *(const float4*)&gb[kk*4];
    float4 o;
    o.x = (acc[kk*4+0] - mean) * rstd * w4.x + b4.x;
    o.y = (acc[kk*4+1] - mean) * rstd * w4.y + b4.y;
    o.z = (acc[kk*4+2] - mean) * rstd * w4.z + b4.z;
    o.w = (acc[kk*4+3] - mean) * rstd * w4.w + b4.w;
    *(float4*)&op[kk*4] = o;
  }
}

extern "C" void kernel_launch(void* const* d_in, const int* in_sizes, int n_in,
                              void* d_out, int out_size, void* d_ws, size_t ws_size,
                              hipStream_t stream) {
  (void)in_sizes; (void)n_in; (void)out_size; (void)d_ws; (void)ws_size;
  const float* q    = (const float*)d_in[0];
  const float* k    = (const float*)d_in[1];
  const float* v    = (const float*)d_in[2];
  const float* Wi_w = (const float*)d_in[3];
  const float* Wi_b = (const float*)d_in[4];
  const float* Wf_w = (const float*)d_in[5];
  const float* Wf_b = (const float*)d_in[6];
  const float* gnw  = (const float*)d_in[7];
  const float* gnb  = (const float*)d_in[8];
  float* out = (float*)d_out;

  convert_kernel<<<dim3(4144), 256, 0, stream>>>(q, k, Wi_w, Wf_w);
  vtrans_kernel<<<dim3(NH, SEQ/64, HD/64), 256, 0, stream>>>(v);
  gates_kernel<<<dim3(128), 256, 0, stream>>>();
  scan_kernel<<<dim3(NH), 256, 0, stream>>>(Wi_b, Wf_b);
  attn1_kernel<<<dim3(NH, 80), 256, 0, stream>>>();
  reduce_kernel<<<dim3(NH, SEQ/64), 256, 0, stream>>>(gnw, gnb, out);
}